// Round 15
// baseline (172.972 us; speedup 1.0000x reference)
//
#include <hip/hip_runtime.h>
#include <hip/hip_bf16.h>

typedef __attribute__((ext_vector_type(8))) short bf16x8;
typedef __attribute__((ext_vector_type(4))) float f32x4;
typedef unsigned short u16;
typedef unsigned int u32;

#define DEV static __device__ __forceinline__

DEV float bf2f(u16 u){ u32 x = ((u32)u)<<16; float f; __builtin_memcpy(&f,&x,4); return f; }
DEV u16 f2bf(float f){ u32 x; __builtin_memcpy(&x,&f,4); return (u16)((x + 0x7fffu + ((x>>16)&1u))>>16); }
DEV float elu1(float x){ return x > 0.f ? x + 1.f : __expf(x); }   // elu(x)+1

DEV void gload16(const u16* g, u16* l){
  __builtin_amdgcn_global_load_lds(
      (const __attribute__((address_space(1))) unsigned int*)(g),
      (__attribute__((address_space(3))) unsigned int*)(l), 16, 0, 0);
}

#define MFMA(a,b,c) __builtin_amdgcn_mfma_f32_16x16x32_bf16((a),(b),(c),0,0,0)

#define NB 2
#define NT 4096
#define NH 8
#define DH 128
#define NS 8
#define SL 512
#define ND 1024
#define N3 3072
#define EPS 1e-6f

// ---------------- k_prep: fused  xb = bf16(x)  +  wt[n][k] = w[k][n]  + cs zero --------
__global__ __launch_bounds__(256) void k_prep(const float* __restrict__ x,
                                              const float* __restrict__ wq,
                                              const float* __restrict__ wk,
                                              const float* __restrict__ wv,
                                              u16* __restrict__ xb,
                                              u16* __restrict__ wt,
                                              float* __restrict__ cs){
  const int bid = blockIdx.x, tid = threadIdx.x;
  if (bid < 4096){
    const int i = bid*256 + tid;
    const float4 v0 = *(const float4*)(x + (size_t)i*8);
    const float4 v1 = *(const float4*)(x + (size_t)i*8 + 4);
    bf16x8 o;
    o[0]=(short)f2bf(v0.x); o[1]=(short)f2bf(v0.y); o[2]=(short)f2bf(v0.z); o[3]=(short)f2bf(v0.w);
    o[4]=(short)f2bf(v1.x); o[5]=(short)f2bf(v1.y); o[6]=(short)f2bf(v1.z); o[7]=(short)f2bf(v1.w);
    *(bf16x8*)(xb + (size_t)i*8) = o;
    return;
  }
  __shared__ float t[32][33];
  const int wi = bid - 4096;              // 0..3071
  const int z = wi >> 10, rem = wi & 1023;
  const int kb = rem & 31, nb = rem >> 5;
  const float* w = (z==0) ? wq : (z==1 ? wk : wv);
  const int k0 = kb*32, n0 = nb*32;
  const int tx = tid & 31, ty = tid >> 5;   // 32 x 8
  if (wi == 0){
#pragma unroll
    for (int i=0;i<64;i++) cs[tid + i*256] = 0.f;
  }
#pragma unroll
  for (int i=0;i<4;i++) t[ty+i*8][tx] = w[(size_t)(k0+ty+i*8)*ND + n0+tx];
  __syncthreads();
#pragma unroll
  for (int i=0;i<4;i++)
    wt[(size_t)(z*ND + n0+ty+i*8)*ND + k0+tx] = f2bf(t[tx][ty+i*8]);
}

// ---------------- k2: qkv = x @ W + b, fused transpose outputs (r12-proven sync) -------
// double-buffered LDS + raw s_barrier + counted vmcnt(8); compute split into
// load-all-frags then two setprio-wrapped MFMA clusters (T5).
__global__ __launch_bounds__(256) void k_gemm(const u16* __restrict__ xb,
                                              const u16* __restrict__ wt,
                                              const float* __restrict__ bq,
                                              const float* __restrict__ bk,
                                              const float* __restrict__ bv,
                                              u16* __restrict__ qkv,
                                              u16* __restrict__ pkTo,
                                              u16* __restrict__ vto,
                                              float* __restrict__ cs){
  __shared__ __align__(16) u16 As[2][128*64];
  __shared__ __align__(16) u16 Bs[2][128*64];
  const int m0 = blockIdx.x*128, n0 = blockIdx.y*128;
  const int tid = threadIdx.x;
  const int w = tid>>6, lane = tid&63, g = lane>>4, li = lane&15;
  const int wr = w>>1, wc = w&1;
  const int srow = lane>>3;
  const int ssl  = (lane&7) ^ srow;
  f32x4 z4 = {0.f,0.f,0.f,0.f};
  f32x4 acc[4][4];
#pragma unroll
  for (int mi=0;mi<4;mi++)
#pragma unroll
    for (int ni=0;ni<4;ni++) acc[mi][ni] = z4;

#define STAGE(kt_) do{                                                          \
    const int k0_ = (kt_)*64;                                                   \
    u16* A_ = (u16*)As[(kt_)&1];                                                \
    u16* B_ = (u16*)Bs[(kt_)&1];                                                \
    _Pragma("unroll")                                                           \
    for (int i_=0;i_<4;i_++){                                                   \
      const int c_ = i_*4 + w;                                                  \
      const int row_ = c_*8 + srow;                                             \
      gload16(xb + (size_t)(m0+row_)*ND + k0_ + ssl*8, A_ + c_*512);            \
      gload16(wt + (size_t)(n0+row_)*ND + k0_ + ssl*8, B_ + c_*512);            \
    }                                                                           \
  }while(0)

  STAGE(0);
  for (int kt=0; kt<16; ++kt){
    if (kt < 15){ STAGE(kt+1); asm volatile("s_waitcnt vmcnt(8)" ::: "memory"); }
    else        {              asm volatile("s_waitcnt vmcnt(0)" ::: "memory"); }
    __builtin_amdgcn_s_barrier();
    __builtin_amdgcn_sched_barrier(0);
    const u16* Ab = (const u16*)As[kt&1];
    const u16* Bb = (const u16*)Bs[kt&1];
    // issue ALL fragment reads up front; kk=1 latency hides under kk=0 MFMAs
    bf16x8 a[2][4], bb[2][4];
#pragma unroll
    for (int kk=0;kk<2;kk++){
      const int slot = kk*4 + g;
#pragma unroll
      for (int mi=0;mi<4;mi++){
        const int row = wr*64 + mi*16 + li;
        a[kk][mi] = *(const bf16x8*)(Ab + row*64 + ((slot^(row&7))<<3));
      }
#pragma unroll
      for (int ni=0;ni<4;ni++){
        const int row = wc*64 + ni*16 + li;
        bb[kk][ni] = *(const bf16x8*)(Bb + row*64 + ((slot^(row&7))<<3));
      }
    }
#pragma unroll
    for (int kk=0;kk<2;kk++){
      __builtin_amdgcn_s_setprio(1);
#pragma unroll
      for (int mi=0;mi<4;mi++)
#pragma unroll
        for (int ni=0;ni<4;ni++)
          acc[mi][ni] = MFMA(a[kk][mi], bb[kk][ni], acc[mi][ni]);
      __builtin_amdgcn_s_setprio(0);
    }
    __builtin_amdgcn_sched_barrier(0);
    __builtin_amdgcn_s_barrier();
    __builtin_amdgcn_sched_barrier(0);
  }
#undef STAGE

  const int part = n0 >> 10;            // 0=q 1=k 2=v
  const int hh = (n0 >> 7) & 7;
  const int bb2 = m0 >> 12;
  const int tloc = m0 & (NT-1);
  const int rb = lane>>3, cb = lane&7;
  u16* SCw = (w < 2 ? (u16*)As[0] : (u16*)Bs[0]) + (w&1)*4096;  // 64x64 u16 per wave

  if (part < 2){
#pragma unroll
    for (int ni=0;ni<4;ni++){
      const int n = n0 + wc*64 + ni*16 + li;
      const float bias = (part==0) ? bq[n] : bk[n-ND];
#pragma unroll
      for (int mi=0;mi<4;mi++)
#pragma unroll
        for (int rr=0;rr<4;rr++){
          const int ml = mi*16 + 4*g + rr;
          const int nl = ni*16 + li;
          SCw[ml*64 + (((nl>>3)^(ml&7))<<3) + (nl&7)] = f2bf(acc[mi][ni][rr] + bias);
        }
    }
    __syncthreads();
#pragma unroll
    for (int j=0;j<8;j++){
      const int r = j*8 + rb;
      bf16x8 v = *(const bf16x8*)(SCw + r*64 + ((cb^(r&7))<<3));
      *(bf16x8*)(qkv + (size_t)(m0 + wr*64 + r)*N3 + n0 + wc*64 + cb*8) = v;
    }
  }
  if (part >= 1){
    __syncthreads();
    float csum[4] = {0.f,0.f,0.f,0.f};
#pragma unroll
    for (int ni=0;ni<4;ni++){
      const int n = n0 + wc*64 + ni*16 + li;
      const float bias = (part==1) ? bk[n-ND] : bv[n-2*ND];
      const int nl = ni*16 + li;
#pragma unroll
      for (int mi=0;mi<4;mi++){
        float v0 = acc[mi][ni][0] + bias;
        float v1 = acc[mi][ni][1] + bias;
        float v2 = acc[mi][ni][2] + bias;
        float v3 = acc[mi][ni][3] + bias;
        if (part==1){
          v0 = elu1(v0); v1 = elu1(v1); v2 = elu1(v2); v3 = elu1(v3);
          csum[ni] += v0+v1+v2+v3;
        }
        short4 pk;
        pk.x = (short)f2bf(v0); pk.y = (short)f2bf(v1);
        pk.z = (short)f2bf(v2); pk.w = (short)f2bf(v3);
        const int gran = (2*mi + (g>>1)) ^ (nl&7);
        *(short4*)(SCw + nl*64 + (gran<<3) + 4*(g&1)) = pk;
      }
    }
    __syncthreads();
    u16* dstT = (part==1) ? pkTo : vto;
    const int bh = bb2*8 + hh;
#pragma unroll
    for (int j=0;j<8;j++){
      const int r = j*8 + rb;
      bf16x8 v = *(const bf16x8*)(SCw + r*64 + ((cb^(r&7))<<3));
      *(bf16x8*)(dstT + (size_t)(bh*DH + wc*64 + r)*NT + tloc + wr*64 + cb*8) = v;
    }
    if (part==1){
      const int s = tloc >> 9;
      const int bhs = bb2*64 + hh*8 + s;
#pragma unroll
      for (int ni=0;ni<4;ni++){
        float c = csum[ni];
        c += __shfl_xor(c,16); c += __shfl_xor(c,32);
        if (g==0)
          atomicAdd(&cs[(size_t)bhs*DH + wc*64 + ni*16 + li], c);
      }
    }
  }
}

// ---------------- k5b: dinvK[bhs][r] = 1/(phik[r].z + eps); z = prefix(cs) -------------
__global__ __launch_bounds__(512) void k_dinv(const u16* __restrict__ qkv,
                                              const float* __restrict__ cs,
                                              float* __restrict__ dinvK){
  const int bhs = blockIdx.x, half = blockIdx.y;
  const int b = bhs>>6, h = (bhs>>3)&7, s = bhs&7;
  const int tid = threadIdx.x, w = tid>>6, lane = tid&63, grp = lane>>4, li = lane&15;
  __shared__ float zl[128];
  if (tid < 128){
    float a = 0.f;
    for (int sp=0; sp<s; ++sp) a += cs[(size_t)(bhs - s + sp)*DH + tid];
    zl[tid] = a;
  }
  __syncthreads();
#pragma unroll
  for (int it=0; it<8; ++it){
    const int r = half*256 + w*32 + it*4 + grp;
    bf16x8 v = *(const bf16x8*)(qkv + (size_t)(b*NT + s*SL + r)*N3 + ND + h*DH + li*8);
    float p = 0.f;
#pragma unroll
    for (int j=0;j<8;j++) p += elu1(bf2f((u16)v[j])) * zl[li*8+j];
    p += __shfl_xor(p,1); p += __shfl_xor(p,2);
    p += __shfl_xor(p,4); p += __shfl_xor(p,8);
    if (li == 0) dinvK[(size_t)bhs*SL + r] = 1.f/(p + EPS);
  }
}

// ---------------- k6: G = phik^T D^-1 phik ; Bm = phik^T v  (128 bhs x 4 col-chunks) ----
__global__ __launch_bounds__(512) void k_gram(const u16* __restrict__ pkT,
                                              const u16* __restrict__ vtb,
                                              const float* __restrict__ dinvK,
                                              u16* __restrict__ G, float* __restrict__ Bm){
  const int bhs = blockIdx.x, ec = blockIdx.y;
  const int bh = bhs>>3, s = bhs&7, tb = s*SL;
  const int tid = threadIdx.x, w = tid>>6, lane = tid&63, g = lane>>4, li = lane&15;
  __shared__ __align__(16) u16 Bk[32*512];
  __shared__ __align__(16) u16 Bv[32*512];
  __shared__ float dv[512];
  dv[tid] = dinvK[(size_t)bhs*SL + tid];
#pragma unroll
  for (int i=0;i<4;i++){
    const int ee = i*8 + w;
    const size_t rowo = ((size_t)bh*DH + ec*32 + ee)*NT + tb + ((lane^w)<<3);
    gload16(pkT + rowo, Bk + ee*512);
    gload16(vtb + rowo, Bv + ee*512);
  }
  __syncthreads();
  f32x4 z4 = {0.f,0.f,0.f,0.f};
  f32x4 Ga[2] = {z4,z4}, Ba[2] = {z4,z4};
  const u16* arow = pkT + ((size_t)bh*DH + 16*w + li)*NT + tb;
  for (int ks=0; ks<16; ++ks){
    const int r0 = ks*32 + g*8;
    bf16x8 araw = *(const bf16x8*)(arow + r0);
    float4 d0 = *(const float4*)(dv + r0);
    float4 d1 = *(const float4*)(dv + r0 + 4);
    bf16x8 ascl;
    ascl[0] = (short)f2bf(bf2f((u16)araw[0]) * d0.x);
    ascl[1] = (short)f2bf(bf2f((u16)araw[1]) * d0.y);
    ascl[2] = (short)f2bf(bf2f((u16)araw[2]) * d0.z);
    ascl[3] = (short)f2bf(bf2f((u16)araw[3]) * d0.w);
    ascl[4] = (short)f2bf(bf2f((u16)araw[4]) * d1.x);
    ascl[5] = (short)f2bf(bf2f((u16)araw[5]) * d1.y);
    ascl[6] = (short)f2bf(bf2f((u16)araw[6]) * d1.z);
    ascl[7] = (short)f2bf(bf2f((u16)araw[7]) * d1.w);
    const int slot = ks*4 + g;
#pragma unroll
    for (int ni=0;ni<2;ni++){
      const int ee = ni*16 + li;
      bf16x8 bk8 = *(const bf16x8*)(Bk + ee*512 + ((slot^(li&7))<<3));
      bf16x8 bv8 = *(const bf16x8*)(Bv + ee*512 + ((slot^(li&7))<<3));
      Ga[ni] = MFMA(ascl, bk8, Ga[ni]);
      Ba[ni] = MFMA(araw, bv8, Ba[ni]);
    }
  }
#pragma unroll
  for (int ni=0;ni<2;ni++)
#pragma unroll
    for (int rr=0;rr<4;rr++){
      const int dd = 16*w + 4*g + rr;
      const int ee = ec*32 + ni*16 + li;
      G[((size_t)bhs*DH + dd)*DH + ee] = f2bf(Ga[ni][rr]);
      Bm[((size_t)bhs*DH + dd)*DH + ee] = Ba[ni][rr];
    }
}

// ---------------- k7: scan, parallel over 8 e-chunks: M[:,e] independent -----------
__global__ __launch_bounds__(512) void k_scan(const u16* __restrict__ G,
                                              const float* __restrict__ Bm,
                                              u16* __restrict__ MTs){
  const int bh = blockIdx.x, ec = blockIdx.y;
  const int tid = threadIdx.x, w = tid>>6, lane = tid&63, g = lane>>4, li = lane&15;
  __shared__ float MF[16*132];                 // f32 M^T chunk [e][d], pad 132
  __shared__ __align__(16) u16 MB[16*128];     // bf16 staged, granule-swizzled
  for (int i = tid; i < 16*132; i += 512) MF[i] = 0.f;
  __syncthreads();
  const int dr = w*16 + li;
  for (int s=0;s<NS;s++){
    const size_t bhs = (size_t)bh*NS + s;
    if (tid < 256){
      const int e = tid>>4, dg = tid&15;
      const float* src = MF + e*132 + dg*8;
      bf16x8 v;
#pragma unroll
      for (int j=0;j<8;j++) v[j] = (short)f2bf(src[j]);
      *(bf16x8*)(MTs + bhs*16384 + (size_t)(ec*16+e)*128 + dg*8) = v;
      *(bf16x8*)(MB + e*128 + ((dg^(e&7))<<3)) = v;
    }
    __syncthreads();
    f32x4 acc = {0.f,0.f,0.f,0.f};
#pragma unroll
    for (int ks=0;ks<4;ks++){
      bf16x8 a = *(const bf16x8*)(G + ((size_t)bhs*DH + dr)*DH + ks*32 + g*8);
      const int sl = ks*4 + g;
      bf16x8 bfr = *(const bf16x8*)(MB + li*128 + ((sl^(li&7))<<3));
      acc = MFMA(a, bfr, acc);
    }
#pragma unroll
    for (int rr=0;rr<4;rr++){
      const int d = w*16 + 4*g + rr;
      const float delta = Bm[((size_t)bhs*DH + d)*DH + ec*16 + li] - acc[rr];
      MF[li*132 + d] += delta;
    }
    __syncthreads();
  }
}

// ---------------- k8: fused local causal attention + memory retrieval ----------------
__global__ __launch_bounds__(512) void k_attn(const u16* __restrict__ qkv,
                                              const u16* __restrict__ vtb,
                                              const u16* __restrict__ MTs,
                                              const float* __restrict__ cs,
                                              const float* __restrict__ beta,
                                              float* __restrict__ out){
  const int bhs = blockIdx.x, half = blockIdx.y;
  const int b = bhs>>6, h = (bhs>>3)&7, s = bhs&7, bh = bhs>>3;
  const int tid = threadIdx.x, w = tid>>6, lane = tid&63, g = lane>>4, li = lane&15;
  const int jq = (w < 4) ? (half + 2*w) : (15 - half - 2*(w-4));
  const int qb = jq*32;
  const float gate = 1.f/(1.f + __expf(-beta[h]));
  const float SCL = 0.08838834764831845f * 1.4426950408889634f;  // isd * log2(e)
  __shared__ __align__(16) u16 P[8*1024];
  __shared__ float zl[128];
  __shared__ float dinvW[8][32];
  u16* Pw = P + w*1024;

  if (tid < 128){
    float a = 0.f;
    for (int sp=0; sp<s; ++sp) a += cs[(size_t)(bhs - s + sp)*DH + tid];
    zl[tid] = a;
  }
  __syncthreads();

  {
    const int r = qb + (lane&31);
    const int dh = (lane>>5)*64;
    const u16* qrow = qkv + (size_t)(b*NT + s*SL + r)*N3 + h*DH + dh;
    float p = 0.f;
#pragma unroll
    for (int j=0;j<64;j+=8){
      bf16x8 v = *(const bf16x8*)(qrow + j);
#pragma unroll
      for (int t=0;t<8;t++) p += elu1(bf2f((u16)v[t])) * zl[dh + j + t];
    }
    p += __shfl_xor(p, 32);
    if (lane < 32) dinvW[w][lane] = 1.f/(p + EPS);
  }

  bf16x8 qf[2][4];
#pragma unroll
  for (int mf=0; mf<2; ++mf)
#pragma unroll
    for (int kf=0; kf<4; ++kf)
      qf[mf][kf] = *(const bf16x8*)(qkv + (size_t)(b*NT + s*SL + qb + mf*16 + li)*N3 + h*DH + kf*32 + g*8);

  bf16x8 one8;
#pragma unroll
  for (int j=0;j<8;j++) one8[j] = (short)0x3F80;   // bf16 1.0

  f32x4 z4 = {0.f,0.f,0.f,0.f};
  f32x4 O[2][8];
  f32x4 lsum[2] = {z4, z4};
#pragma unroll
  for (int mf=0;mf<2;++mf)
#pragma unroll
    for (int nf=0;nf<8;++nf) O[mf][nf] = z4;

  const int nch = jq + 1;
  for (int c=0; c<nch; ++c){
    const int kb = c*32;
    f32x4 sa[2][2];
#pragma unroll
    for (int mf=0;mf<2;++mf)
#pragma unroll
      for (int nf=0;nf<2;++nf) sa[mf][nf] = z4;
    __builtin_amdgcn_s_setprio(1);
#pragma unroll
    for (int kf=0; kf<4; ++kf)
#pragma unroll
      for (int nf=0; nf<2; ++nf){
        bf16x8 bk8 = *(const bf16x8*)(qkv + (size_t)(b*NT + s*SL + kb + nf*16 + li)*N3 + ND + h*DH + kf*32 + g*8);
        sa[0][nf] = MFMA(qf[0][kf], bk8, sa[0][nf]);
        sa[1][nf] = MFMA(qf[1][kf], bk8, sa[1][nf]);
      }
    __builtin_amdgcn_s_setprio(0);
#pragma unroll
    for (int mf=0;mf<2;++mf)
#pragma unroll
      for (int nf=0;nf<2;++nf)
#pragma unroll
        for (int rr=0;rr<4;++rr){
          const int row = qb + mf*16 + 4*g + rr, col = kb + nf*16 + li;
          const float p = (col > row) ? 0.f : exp2f(sa[mf][nf][rr]*SCL);
          const int rl = mf*16 + 4*g + rr, cl = nf*16 + li;
          Pw[rl*32 + (((cl>>3)^(rl&3))<<3) + (cl&7)] = f2bf(p);
        }
    bf16x8 pa[2];
#pragma unroll
    for (int mf=0;mf<2;++mf){
      const int row = mf*16 + li;
      pa[mf] = *(const bf16x8*)(Pw + row*32 + ((g^(row&3))<<3));
    }
    __builtin_amdgcn_s_setprio(1);
#pragma unroll
    for (int nf=0;nf<8;++nf){
      bf16x8 bv8 = *(const bf16x8*)(vtb + ((size_t)bh*DH + nf*16 + li)*NT + s*SL + kb + g*8);
      O[0][nf] = MFMA(pa[0], bv8, O[0][nf]);
      O[1][nf] = MFMA(pa[1], bv8, O[1][nf]);
    }
    lsum[0] = MFMA(pa[0], one8, lsum[0]);
    lsum[1] = MFMA(pa[1], one8, lsum[1]);
    __builtin_amdgcn_s_setprio(0);
  }

  f32x4 Am[2][8];
#pragma unroll
  for (int mf=0;mf<2;++mf)
#pragma unroll
    for (int nf=0;nf<8;++nf) Am[mf][nf] = z4;
#pragma unroll
  for (int ks=0;ks<4;++ks){
    bf16x8 pq[2];
#pragma unroll
    for (int mf=0;mf<2;++mf){
      bf16x8 raw = qf[mf][ks];
#pragma unroll
      for (int j=0;j<8;j++) raw[j] = (short)f2bf(elu1(bf2f((u16)raw[j])));
      pq[mf] = raw;
    }
#pragma unroll
    for (int nf=0;nf<8;++nf){
      bf16x8 bfr = *(const bf16x8*)(MTs + ((size_t)bhs*DH + nf*16 + li)*DH + ks*32 + g*8);
      Am[0][nf] = MFMA(pq[0], bfr, Am[0][nf]);
      Am[1][nf] = MFMA(pq[1], bfr, Am[1][nf]);
    }
  }

  const float og = 1.f - gate;
#pragma unroll
  for (int mf=0;mf<2;++mf)
#pragma unroll
    for (int rr=0;rr<4;++rr){
      const int row = qb + mf*16 + 4*g + rr;
      const float invd = og / lsum[mf][rr];
      const float dv = gate * dinvW[w][row - qb];
#pragma unroll
      for (int nf=0;nf<8;++nf)
        out[(size_t)(b*NT + s*SL + row)*ND + h*DH + nf*16 + li] =
            O[mf][nf][rr]*invd + Am[mf][nf][rr]*dv;
    }
}

// ---------------- launch ----------------
extern "C" void kernel_launch(void* const* d_in, const int* in_sizes, int n_in,
                              void* d_out, int out_size, void* d_ws, size_t ws_size,
                              hipStream_t stream) {
  (void)in_sizes; (void)n_in; (void)out_size; (void)ws_size;
  const float* x    = (const float*)d_in[0];
  const float* wq   = (const float*)d_in[1];
  const float* bq   = (const float*)d_in[2];
  const float* wk   = (const float*)d_in[3];
  const float* bk   = (const float*)d_in[4];
  const float* wv   = (const float*)d_in[5];
  const float* bv   = (const float*)d_in[6];
  const float* beta = (const float*)d_in[7];
  float* out = (float*)d_out;
  char* ws = (char*)d_ws;

  u16*   wt  = (u16*)  (ws + 0);          //  6,291,456 B (dead after k_gemm)
  u16*   qkv = (u16*)  (ws + 6291456);    // 50,331,648 B (only q,k written)
  u16*   vt  = (u16*)  (ws + 56623104);   // 16,777,216 B
  u16*   pkT = (u16*)  (ws + 73400320);   // 16,777,216 B
  u16*   G   = (u16*)  (ws + 90177536);   //  4,194,304 B
  float* Bm  = (float*)(ws + 94371840);   //  8,388,608 B
  u16*   MTs = (u16*)  (ws + 102760448);  //  4,194,304 B
  float* cs  = (float*)(ws + 106954752);  //     65,536 B
  float* dinvK = (float*)(ws + 107020288);//    262,144 B
  // xb aliases G+Bm+MTs (16 MiB, written only after k_gemm by k_gram/k_scan)
  u16*   xb  = (u16*)  (ws + 90177536);

  hipLaunchKernelGGL(k_prep,  dim3(7168),    dim3(256),  0, stream, x, wq, wk, wv, xb, wt, cs);
  hipLaunchKernelGGL(k_gemm,  dim3(64,24),   dim3(256),  0, stream, xb, wt, bq, bk, bv, qkv, pkT, vt, cs);
  hipLaunchKernelGGL(k_dinv,  dim3(128,2),   dim3(512),  0, stream, qkv, cs, dinvK);
  hipLaunchKernelGGL(k_gram,  dim3(128,4),   dim3(512),  0, stream, pkT, vt, dinvK, G, Bm);
  hipLaunchKernelGGL(k_scan,  dim3(16,8),    dim3(512),  0, stream, G, Bm, MTs);
  hipLaunchKernelGGL(k_attn,  dim3(128,2),   dim3(512),  0, stream, qkv, vt, MTs, cs, beta, out);
}

// Round 16
// 169.601 us; speedup vs baseline: 1.0199x; 1.0199x over previous
//
#include <hip/hip_runtime.h>
#include <hip/hip_bf16.h>

typedef __attribute__((ext_vector_type(8))) short bf16x8;
typedef __attribute__((ext_vector_type(4))) float f32x4;
typedef unsigned short u16;
typedef unsigned int u32;

#define DEV static __device__ __forceinline__

DEV float bf2f(u16 u){ u32 x = ((u32)u)<<16; float f; __builtin_memcpy(&f,&x,4); return f; }
DEV u16 f2bf(float f){ u32 x; __builtin_memcpy(&x,&f,4); return (u16)((x + 0x7fffu + ((x>>16)&1u))>>16); }
DEV float elu1(float x){ return x > 0.f ? x + 1.f : __expf(x); }   // elu(x)+1

DEV void gload16(const u16* g, u16* l){
  __builtin_amdgcn_global_load_lds(
      (const __attribute__((address_space(1))) unsigned int*)(g),
      (__attribute__((address_space(3))) unsigned int*)(l), 16, 0, 0);
}

#define MFMA(a,b,c) __builtin_amdgcn_mfma_f32_16x16x32_bf16((a),(b),(c),0,0,0)

#define NB 2
#define NT 4096
#define NH 8
#define DH 128
#define NS 8
#define SL 512
#define ND 1024
#define N3 3072
#define EPS 1e-6f

// ---------------- k_prep: fused  xb = bf16(x)  +  wt[n][k] = w[k][n]  + cs zero --------
__global__ __launch_bounds__(256) void k_prep(const float* __restrict__ x,
                                              const float* __restrict__ wq,
                                              const float* __restrict__ wk,
                                              const float* __restrict__ wv,
                                              u16* __restrict__ xb,
                                              u16* __restrict__ wt,
                                              float* __restrict__ cs){
  const int bid = blockIdx.x, tid = threadIdx.x;
  if (bid < 4096){
    const int i = bid*256 + tid;
    const float4 v0 = *(const float4*)(x + (size_t)i*8);
    const float4 v1 = *(const float4*)(x + (size_t)i*8 + 4);
    bf16x8 o;
    o[0]=(short)f2bf(v0.x); o[1]=(short)f2bf(v0.y); o[2]=(short)f2bf(v0.z); o[3]=(short)f2bf(v0.w);
    o[4]=(short)f2bf(v1.x); o[5]=(short)f2bf(v1.y); o[6]=(short)f2bf(v1.z); o[7]=(short)f2bf(v1.w);
    *(bf16x8*)(xb + (size_t)i*8) = o;
    return;
  }
  __shared__ float t[32][33];
  const int wi = bid - 4096;              // 0..3071
  const int z = wi >> 10, rem = wi & 1023;
  const int kb = rem & 31, nb = rem >> 5;
  const float* w = (z==0) ? wq : (z==1 ? wk : wv);
  const int k0 = kb*32, n0 = nb*32;
  const int tx = tid & 31, ty = tid >> 5;   // 32 x 8
  if (wi == 0){
#pragma unroll
    for (int i=0;i<64;i++) cs[tid + i*256] = 0.f;
  }
#pragma unroll
  for (int i=0;i<4;i++) t[ty+i*8][tx] = w[(size_t)(k0+ty+i*8)*ND + n0+tx];
  __syncthreads();
#pragma unroll
  for (int i=0;i<4;i++)
    wt[(size_t)(z*ND + n0+ty+i*8)*ND + k0+tx] = f2bf(t[tx][ty+i*8]);
}

// ---------------- k2: qkv = x @ W + b, fused transpose outputs (r12-proven) ------------
// double-buffered LDS + raw s_barrier + counted vmcnt(8)
__global__ __launch_bounds__(256) void k_gemm(const u16* __restrict__ xb,
                                              const u16* __restrict__ wt,
                                              const float* __restrict__ bq,
                                              const float* __restrict__ bk,
                                              const float* __restrict__ bv,
                                              u16* __restrict__ qkv,
                                              u16* __restrict__ pkTo,
                                              u16* __restrict__ vto,
                                              float* __restrict__ cs){
  __shared__ __align__(16) u16 As[2][128*64];
  __shared__ __align__(16) u16 Bs[2][128*64];
  const int m0 = blockIdx.x*128, n0 = blockIdx.y*128;
  const int tid = threadIdx.x;
  const int w = tid>>6, lane = tid&63, g = lane>>4, li = lane&15;
  const int wr = w>>1, wc = w&1;
  const int srow = lane>>3;
  const int ssl  = (lane&7) ^ srow;
  f32x4 z4 = {0.f,0.f,0.f,0.f};
  f32x4 acc[4][4];
#pragma unroll
  for (int mi=0;mi<4;mi++)
#pragma unroll
    for (int ni=0;ni<4;ni++) acc[mi][ni] = z4;

#define STAGE(kt_) do{                                                          \
    const int k0_ = (kt_)*64;                                                   \
    u16* A_ = (u16*)As[(kt_)&1];                                                \
    u16* B_ = (u16*)Bs[(kt_)&1];                                                \
    _Pragma("unroll")                                                           \
    for (int i_=0;i_<4;i_++){                                                   \
      const int c_ = i_*4 + w;                                                  \
      const int row_ = c_*8 + srow;                                             \
      gload16(xb + (size_t)(m0+row_)*ND + k0_ + ssl*8, A_ + c_*512);            \
      gload16(wt + (size_t)(n0+row_)*ND + k0_ + ssl*8, B_ + c_*512);            \
    }                                                                           \
  }while(0)

  STAGE(0);
  for (int kt=0; kt<16; ++kt){
    if (kt < 15){ STAGE(kt+1); asm volatile("s_waitcnt vmcnt(8)" ::: "memory"); }
    else        {              asm volatile("s_waitcnt vmcnt(0)" ::: "memory"); }
    __builtin_amdgcn_s_barrier();
    __builtin_amdgcn_sched_barrier(0);
    const u16* Ab = (const u16*)As[kt&1];
    const u16* Bb = (const u16*)Bs[kt&1];
#pragma unroll
    for (int kk=0;kk<2;kk++){
      bf16x8 a[4], bb[4];
#pragma unroll
      for (int mi=0;mi<4;mi++){
        int row = wr*64 + mi*16 + li;
        int slot = kk*4 + g;
        a[mi] = *(const bf16x8*)(Ab + row*64 + ((slot^(row&7))<<3));
      }
#pragma unroll
      for (int ni=0;ni<4;ni++){
        int row = wc*64 + ni*16 + li;
        int slot = kk*4 + g;
        bb[ni] = *(const bf16x8*)(Bb + row*64 + ((slot^(row&7))<<3));
      }
#pragma unroll
      for (int mi=0;mi<4;mi++)
#pragma unroll
        for (int ni=0;ni<4;ni++)
          acc[mi][ni] = MFMA(a[mi], bb[ni], acc[mi][ni]);
    }
    __builtin_amdgcn_sched_barrier(0);
    __builtin_amdgcn_s_barrier();
    __builtin_amdgcn_sched_barrier(0);
  }
#undef STAGE

  const int part = n0 >> 10;            // 0=q 1=k 2=v
  const int hh = (n0 >> 7) & 7;
  const int bb2 = m0 >> 12;
  const int tloc = m0 & (NT-1);
  const int rb = lane>>3, cb = lane&7;
  u16* SCw = (w < 2 ? (u16*)As[0] : (u16*)Bs[0]) + (w&1)*4096;  // 64x64 u16 per wave

  if (part < 2){
#pragma unroll
    for (int ni=0;ni<4;ni++){
      const int n = n0 + wc*64 + ni*16 + li;
      const float bias = (part==0) ? bq[n] : bk[n-ND];
#pragma unroll
      for (int mi=0;mi<4;mi++)
#pragma unroll
        for (int rr=0;rr<4;rr++){
          const int ml = mi*16 + 4*g + rr;
          const int nl = ni*16 + li;
          SCw[ml*64 + (((nl>>3)^(ml&7))<<3) + (nl&7)] = f2bf(acc[mi][ni][rr] + bias);
        }
    }
    __syncthreads();
#pragma unroll
    for (int j=0;j<8;j++){
      const int r = j*8 + rb;
      bf16x8 v = *(const bf16x8*)(SCw + r*64 + ((cb^(r&7))<<3));
      *(bf16x8*)(qkv + (size_t)(m0 + wr*64 + r)*N3 + n0 + wc*64 + cb*8) = v;
    }
  }
  if (part >= 1){
    __syncthreads();
    float csum[4] = {0.f,0.f,0.f,0.f};
#pragma unroll
    for (int ni=0;ni<4;ni++){
      const int n = n0 + wc*64 + ni*16 + li;
      const float bias = (part==1) ? bk[n-ND] : bv[n-2*ND];
      const int nl = ni*16 + li;
#pragma unroll
      for (int mi=0;mi<4;mi++){
        float v0 = acc[mi][ni][0] + bias;
        float v1 = acc[mi][ni][1] + bias;
        float v2 = acc[mi][ni][2] + bias;
        float v3 = acc[mi][ni][3] + bias;
        if (part==1){
          v0 = elu1(v0); v1 = elu1(v1); v2 = elu1(v2); v3 = elu1(v3);
          csum[ni] += v0+v1+v2+v3;
        }
        short4 pk;
        pk.x = (short)f2bf(v0); pk.y = (short)f2bf(v1);
        pk.z = (short)f2bf(v2); pk.w = (short)f2bf(v3);
        const int gran = (2*mi + (g>>1)) ^ (nl&7);
        *(short4*)(SCw + nl*64 + (gran<<3) + 4*(g&1)) = pk;
      }
    }
    __syncthreads();
    u16* dstT = (part==1) ? pkTo : vto;
    const int bh = bb2*8 + hh;
#pragma unroll
    for (int j=0;j<8;j++){
      const int r = j*8 + rb;
      bf16x8 v = *(const bf16x8*)(SCw + r*64 + ((cb^(r&7))<<3));
      *(bf16x8*)(dstT + (size_t)(bh*DH + wc*64 + r)*NT + tloc + wr*64 + cb*8) = v;
    }
    if (part==1){
      const int s = tloc >> 9;
      const int bhs = bb2*64 + hh*8 + s;
#pragma unroll
      for (int ni=0;ni<4;ni++){
        float c = csum[ni];
        c += __shfl_xor(c,16); c += __shfl_xor(c,32);
        if (g==0)
          atomicAdd(&cs[(size_t)bhs*DH + wc*64 + ni*16 + li], c);
      }
    }
  }
}

// ---------------- k5b: dinvK[bhs][r] = 1/(phik[r].z + eps); z = prefix(cs) -------------
__global__ __launch_bounds__(512) void k_dinv(const u16* __restrict__ qkv,
                                              const float* __restrict__ cs,
                                              float* __restrict__ dinvK){
  const int bhs = blockIdx.x, half = blockIdx.y;
  const int b = bhs>>6, h = (bhs>>3)&7, s = bhs&7;
  const int tid = threadIdx.x, w = tid>>6, lane = tid&63, grp = lane>>4, li = lane&15;
  __shared__ float zl[128];
  if (tid < 128){
    float a = 0.f;
    for (int sp=0; sp<s; ++sp) a += cs[(size_t)(bhs - s + sp)*DH + tid];
    zl[tid] = a;
  }
  __syncthreads();
#pragma unroll
  for (int it=0; it<8; ++it){
    const int r = half*256 + w*32 + it*4 + grp;
    bf16x8 v = *(const bf16x8*)(qkv + (size_t)(b*NT + s*SL + r)*N3 + ND + h*DH + li*8);
    float p = 0.f;
#pragma unroll
    for (int j=0;j<8;j++) p += elu1(bf2f((u16)v[j])) * zl[li*8+j];
    p += __shfl_xor(p,1); p += __shfl_xor(p,2);
    p += __shfl_xor(p,4); p += __shfl_xor(p,8);
    if (li == 0) dinvK[(size_t)bhs*SL + r] = 1.f/(p + EPS);
  }
}

// ---------------- k6: G = phik^T D^-1 phik ; Bm = phik^T v  (128 bhs x 4 col-chunks) ----
__global__ __launch_bounds__(512) void k_gram(const u16* __restrict__ pkT,
                                              const u16* __restrict__ vtb,
                                              const float* __restrict__ dinvK,
                                              u16* __restrict__ G, float* __restrict__ Bm){
  const int bhs = blockIdx.x, ec = blockIdx.y;
  const int bh = bhs>>3, s = bhs&7, tb = s*SL;
  const int tid = threadIdx.x, w = tid>>6, lane = tid&63, g = lane>>4, li = lane&15;
  __shared__ __align__(16) u16 Bk[32*512];
  __shared__ __align__(16) u16 Bv[32*512];
  __shared__ float dv[512];
  dv[tid] = dinvK[(size_t)bhs*SL + tid];
#pragma unroll
  for (int i=0;i<4;i++){
    const int ee = i*8 + w;
    const size_t rowo = ((size_t)bh*DH + ec*32 + ee)*NT + tb + ((lane^w)<<3);
    gload16(pkT + rowo, Bk + ee*512);
    gload16(vtb + rowo, Bv + ee*512);
  }
  __syncthreads();
  f32x4 z4 = {0.f,0.f,0.f,0.f};
  f32x4 Ga[2] = {z4,z4}, Ba[2] = {z4,z4};
  const u16* arow = pkT + ((size_t)bh*DH + 16*w + li)*NT + tb;
  for (int ks=0; ks<16; ++ks){
    const int r0 = ks*32 + g*8;
    bf16x8 araw = *(const bf16x8*)(arow + r0);
    float4 d0 = *(const float4*)(dv + r0);
    float4 d1 = *(const float4*)(dv + r0 + 4);
    bf16x8 ascl;
    ascl[0] = (short)f2bf(bf2f((u16)araw[0]) * d0.x);
    ascl[1] = (short)f2bf(bf2f((u16)araw[1]) * d0.y);
    ascl[2] = (short)f2bf(bf2f((u16)araw[2]) * d0.z);
    ascl[3] = (short)f2bf(bf2f((u16)araw[3]) * d0.w);
    ascl[4] = (short)f2bf(bf2f((u16)araw[4]) * d1.x);
    ascl[5] = (short)f2bf(bf2f((u16)araw[5]) * d1.y);
    ascl[6] = (short)f2bf(bf2f((u16)araw[6]) * d1.z);
    ascl[7] = (short)f2bf(bf2f((u16)araw[7]) * d1.w);
    const int slot = ks*4 + g;
#pragma unroll
    for (int ni=0;ni<2;ni++){
      const int ee = ni*16 + li;
      bf16x8 bk8 = *(const bf16x8*)(Bk + ee*512 + ((slot^(li&7))<<3));
      bf16x8 bv8 = *(const bf16x8*)(Bv + ee*512 + ((slot^(li&7))<<3));
      Ga[ni] = MFMA(ascl, bk8, Ga[ni]);
      Ba[ni] = MFMA(araw, bv8, Ba[ni]);
    }
  }
#pragma unroll
  for (int ni=0;ni<2;ni++)
#pragma unroll
    for (int rr=0;rr<4;rr++){
      const int dd = 16*w + 4*g + rr;
      const int ee = ec*32 + ni*16 + li;
      G[((size_t)bhs*DH + dd)*DH + ee] = f2bf(Ga[ni][rr]);
      Bm[((size_t)bhs*DH + dd)*DH + ee] = Ba[ni][rr];
    }
}

// ---------------- k7: scan, parallel over 8 e-chunks: M[:,e] independent -----------
__global__ __launch_bounds__(512) void k_scan(const u16* __restrict__ G,
                                              const float* __restrict__ Bm,
                                              u16* __restrict__ MTs){
  const int bh = blockIdx.x, ec = blockIdx.y;
  const int tid = threadIdx.x, w = tid>>6, lane = tid&63, g = lane>>4, li = lane&15;
  __shared__ float MF[16*132];                 // f32 M^T chunk [e][d], pad 132
  __shared__ __align__(16) u16 MB[16*128];     // bf16 staged, granule-swizzled
  for (int i = tid; i < 16*132; i += 512) MF[i] = 0.f;
  __syncthreads();
  const int dr = w*16 + li;
  for (int s=0;s<NS;s++){
    const size_t bhs = (size_t)bh*NS + s;
    if (tid < 256){
      const int e = tid>>4, dg = tid&15;
      const float* src = MF + e*132 + dg*8;
      bf16x8 v;
#pragma unroll
      for (int j=0;j<8;j++) v[j] = (short)f2bf(src[j]);
      *(bf16x8*)(MTs + bhs*16384 + (size_t)(ec*16+e)*128 + dg*8) = v;
      *(bf16x8*)(MB + e*128 + ((dg^(e&7))<<3)) = v;
    }
    __syncthreads();
    f32x4 acc = {0.f,0.f,0.f,0.f};
#pragma unroll
    for (int ks=0;ks<4;ks++){
      bf16x8 a = *(const bf16x8*)(G + ((size_t)bhs*DH + dr)*DH + ks*32 + g*8);
      const int sl = ks*4 + g;
      bf16x8 bfr = *(const bf16x8*)(MB + li*128 + ((sl^(li&7))<<3));
      acc = MFMA(a, bfr, acc);
    }
#pragma unroll
    for (int rr=0;rr<4;rr++){
      const int d = w*16 + 4*g + rr;
      const float delta = Bm[((size_t)bhs*DH + d)*DH + ec*16 + li] - acc[rr];
      MF[li*132 + d] += delta;
    }
    __syncthreads();
  }
}

// ---------------- k8: fused local causal attention + memory retrieval ----------------
__global__ __launch_bounds__(512) void k_attn(const u16* __restrict__ qkv,
                                              const u16* __restrict__ vtb,
                                              const u16* __restrict__ MTs,
                                              const float* __restrict__ cs,
                                              const float* __restrict__ beta,
                                              float* __restrict__ out){
  const int bhs = blockIdx.x, half = blockIdx.y;
  const int b = bhs>>6, h = (bhs>>3)&7, s = bhs&7, bh = bhs>>3;
  const int tid = threadIdx.x, w = tid>>6, lane = tid&63, g = lane>>4, li = lane&15;
  const int jq = (w < 4) ? (half + 2*w) : (15 - half - 2*(w-4));
  const int qb = jq*32;
  const float gate = 1.f/(1.f + __expf(-beta[h]));
  const float SCL = 0.08838834764831845f * 1.4426950408889634f;  // isd * log2(e)
  __shared__ __align__(16) u16 P[8*1024];
  __shared__ float zl[128];
  __shared__ float dinvW[8][32];
  u16* Pw = P + w*1024;

  if (tid < 128){
    float a = 0.f;
    for (int sp=0; sp<s; ++sp) a += cs[(size_t)(bhs - s + sp)*DH + tid];
    zl[tid] = a;
  }
  __syncthreads();

  {
    const int r = qb + (lane&31);
    const int dh = (lane>>5)*64;
    const u16* qrow = qkv + (size_t)(b*NT + s*SL + r)*N3 + h*DH + dh;
    float p = 0.f;
#pragma unroll
    for (int j=0;j<64;j+=8){
      bf16x8 v = *(const bf16x8*)(qrow + j);
#pragma unroll
      for (int t=0;t<8;t++) p += elu1(bf2f((u16)v[t])) * zl[dh + j + t];
    }
    p += __shfl_xor(p, 32);
    if (lane < 32) dinvW[w][lane] = 1.f/(p + EPS);
  }

  bf16x8 qf[2][4];
#pragma unroll
  for (int mf=0; mf<2; ++mf)
#pragma unroll
    for (int kf=0; kf<4; ++kf)
      qf[mf][kf] = *(const bf16x8*)(qkv + (size_t)(b*NT + s*SL + qb + mf*16 + li)*N3 + h*DH + kf*32 + g*8);

  bf16x8 one8;
#pragma unroll
  for (int j=0;j<8;j++) one8[j] = (short)0x3F80;   // bf16 1.0

  f32x4 z4 = {0.f,0.f,0.f,0.f};
  f32x4 O[2][8];
  f32x4 lsum[2] = {z4, z4};
#pragma unroll
  for (int mf=0;mf<2;++mf)
#pragma unroll
    for (int nf=0;nf<8;++nf) O[mf][nf] = z4;

  const int nch = jq + 1;
  for (int c=0; c<nch; ++c){
    const int kb = c*32;
    f32x4 sa[2][2];
#pragma unroll
    for (int mf=0;mf<2;++mf)
#pragma unroll
      for (int nf=0;nf<2;++nf) sa[mf][nf] = z4;
#pragma unroll
    for (int kf=0; kf<4; ++kf)
#pragma unroll
      for (int nf=0; nf<2; ++nf){
        bf16x8 bk8 = *(const bf16x8*)(qkv + (size_t)(b*NT + s*SL + kb + nf*16 + li)*N3 + ND + h*DH + kf*32 + g*8);
        sa[0][nf] = MFMA(qf[0][kf], bk8, sa[0][nf]);
        sa[1][nf] = MFMA(qf[1][kf], bk8, sa[1][nf]);
      }
#pragma unroll
    for (int mf=0;mf<2;++mf)
#pragma unroll
      for (int nf=0;nf<2;++nf)
#pragma unroll
        for (int rr=0;rr<4;++rr){
          const int row = qb + mf*16 + 4*g + rr, col = kb + nf*16 + li;
          const float p = (col > row) ? 0.f : exp2f(sa[mf][nf][rr]*SCL);
          const int rl = mf*16 + 4*g + rr, cl = nf*16 + li;
          Pw[rl*32 + (((cl>>3)^(rl&3))<<3) + (cl&7)] = f2bf(p);
        }
    bf16x8 pa[2];
#pragma unroll
    for (int mf=0;mf<2;++mf){
      const int row = mf*16 + li;
      pa[mf] = *(const bf16x8*)(Pw + row*32 + ((g^(row&3))<<3));
    }
#pragma unroll
    for (int nf=0;nf<8;++nf){
      bf16x8 bv8 = *(const bf16x8*)(vtb + ((size_t)bh*DH + nf*16 + li)*NT + s*SL + kb + g*8);
      O[0][nf] = MFMA(pa[0], bv8, O[0][nf]);
      O[1][nf] = MFMA(pa[1], bv8, O[1][nf]);
    }
    lsum[0] = MFMA(pa[0], one8, lsum[0]);
    lsum[1] = MFMA(pa[1], one8, lsum[1]);
  }

  f32x4 Am[2][8];
#pragma unroll
  for (int mf=0;mf<2;++mf)
#pragma unroll
    for (int nf=0;nf<8;++nf) Am[mf][nf] = z4;
#pragma unroll
  for (int ks=0;ks<4;++ks){
    bf16x8 pq[2];
#pragma unroll
    for (int mf=0;mf<2;++mf){
      bf16x8 raw = qf[mf][ks];
#pragma unroll
      for (int j=0;j<8;j++) raw[j] = (short)f2bf(elu1(bf2f((u16)raw[j])));
      pq[mf] = raw;
    }
#pragma unroll
    for (int nf=0;nf<8;++nf){
      bf16x8 bfr = *(const bf16x8*)(MTs + ((size_t)bhs*DH + nf*16 + li)*DH + ks*32 + g*8);
      Am[0][nf] = MFMA(pq[0], bfr, Am[0][nf]);
      Am[1][nf] = MFMA(pq[1], bfr, Am[1][nf]);
    }
  }

  const float og = 1.f - gate;
#pragma unroll
  for (int mf=0;mf<2;++mf)
#pragma unroll
    for (int rr=0;rr<4;++rr){
      const int row = qb + mf*16 + 4*g + rr;
      const float invd = og / lsum[mf][rr];
      const float dv = gate * dinvW[w][row - qb];
#pragma unroll
      for (int nf=0;nf<8;++nf)
        out[(size_t)(b*NT + s*SL + row)*ND + h*DH + nf*16 + li] =
            O[mf][nf][rr]*invd + Am[mf][nf][rr]*dv;
    }
}

// ---------------- launch ----------------
extern "C" void kernel_launch(void* const* d_in, const int* in_sizes, int n_in,
                              void* d_out, int out_size, void* d_ws, size_t ws_size,
                              hipStream_t stream) {
  (void)in_sizes; (void)n_in; (void)out_size; (void)ws_size;
  const float* x    = (const float*)d_in[0];
  const float* wq   = (const float*)d_in[1];
  const float* bq   = (const float*)d_in[2];
  const float* wk   = (const float*)d_in[3];
  const float* bk   = (const float*)d_in[4];
  const float* wv   = (const float*)d_in[5];
  const float* bv   = (const float*)d_in[6];
  const float* beta = (const float*)d_in[7];
  float* out = (float*)d_out;
  char* ws = (char*)d_ws;

  u16*   wt  = (u16*)  (ws + 0);          //  6,291,456 B (dead after k_gemm)
  u16*   qkv = (u16*)  (ws + 6291456);    // 50,331,648 B (only q,k written)
  u16*   vt  = (u16*)  (ws + 56623104);   // 16,777,216 B
  u16*   pkT = (u16*)  (ws + 73400320);   // 16,777,216 B
  u16*   G   = (u16*)  (ws + 90177536);   //  4,194,304 B
  float* Bm  = (float*)(ws + 94371840);   //  8,388,608 B
  u16*   MTs = (u16*)  (ws + 102760448);  //  4,194,304 B
  float* cs  = (float*)(ws + 106954752);  //     65,536 B
  float* dinvK = (float*)(ws + 107020288);//    262,144 B
  // xb aliases G+Bm+MTs (16 MiB, written only after k_gemm by k_gram/k_scan)
  u16*   xb  = (u16*)  (ws + 90177536);

  hipLaunchKernelGGL(k_prep,  dim3(7168),    dim3(256),  0, stream, x, wq, wk, wv, xb, wt, cs);
  hipLaunchKernelGGL(k_gemm,  dim3(64,24),   dim3(256),  0, stream, xb, wt, bq, bk, bv, qkv, pkT, vt, cs);
  hipLaunchKernelGGL(k_dinv,  dim3(128,2),   dim3(512),  0, stream, qkv, cs, dinvK);
  hipLaunchKernelGGL(k_gram,  dim3(128,4),   dim3(512),  0, stream, pkT, vt, dinvK, G, Bm);
  hipLaunchKernelGGL(k_scan,  dim3(16,8),    dim3(512),  0, stream, G, Bm, MTs);
  hipLaunchKernelGGL(k_attn,  dim3(128,2),   dim3(512),  0, stream, qkv, vt, MTs, cs, beta, out);
}